// Round 1
// baseline (296.207 us; speedup 1.0000x reference)
//
#include <hip/hip_runtime.h>

#define N_VERT 50000
#define F 128
#define K 20
#define NROW 16   // rows per block in GEMM kernel

// ---------------------------------------------------------------------------
// Kernel A: vagg[i,:] = (sum_k w_k * V[idx_k,:]) / denom_i
// One 64-lane wave per vertex row; each lane owns 2 features (float2 = 8B/lane,
// 512B per wave-gather, fully coalesced within a row).
// ---------------------------------------------------------------------------
__global__ __launch_bounds__(256) void agg_kernel(
    const float* __restrict__ v,
    const int*   __restrict__ nh_idx,
    const int*   __restrict__ int_idx,
    const float* __restrict__ nh_e,
    const float* __restrict__ int_e,
    float* __restrict__ vagg)
{
    int row  = blockIdx.x * 4 + (threadIdx.x >> 6);
    int lane = threadIdx.x & 63;
    if (row >= N_VERT) return;

    float ax = 0.f, ay = 0.f;
    float cnt = (float)K;          // nh indices are always valid (0..N-1)
    const long base = (long)row * K;

    #pragma unroll
    for (int k = 0; k < K; ++k) {
        int   j = nh_idx[base + k];
        float w = nh_e [base + k];
        const float2* src = (const float2*)(v + (long)j * F);
        float2 x = src[lane];
        ax = fmaf(w, x.x, ax);
        ay = fmaf(w, x.y, ay);
    }
    #pragma unroll
    for (int k = 0; k < K; ++k) {
        int   j = int_idx[base + k];
        float w = int_e [base + k];
        if (j != -1) {             // wave-uniform branch (j same for all lanes)
            const float2* src = (const float2*)(v + (long)j * F);
            float2 x = src[lane];
            ax = fmaf(w, x.x, ax);
            ay = fmaf(w, x.y, ay);
            cnt += 1.f;
        }
    }
    float inv = 1.f / cnt;
    float2* o = (float2*)(vagg + (long)row * F);
    o[lane] = make_float2(ax * inv, ay * inv);
}

// ---------------------------------------------------------------------------
// Kernel B: out = relu(V @ Wvc + vagg @ Wvn + bv), fused fp32 vector GEMM.
// Block = 256 threads: col c = tid&127, half hs = tid>>7 (hs=0: V*Wvc,
// hs=1: vagg*Wvn). 16 rows per block staged in LDS; halves combined via LDS.
// NOTE: vagg aliases out (each block reads only its own rows before writing
// them back; __syncthreads orders the accesses) -> no __restrict__ on those.
// ---------------------------------------------------------------------------
__global__ __launch_bounds__(256) void gemm_kernel(
    const float* __restrict__ v,
    const float* vagg,             // aliases out
    const float* __restrict__ Wvc,
    const float* __restrict__ Wvn,
    const float* __restrict__ bv,
    float* out)
{
    __shared__ float A[2][NROW][F];   // 16 KB
    __shared__ float P[NROW][F];      //  8 KB

    const int tid = threadIdx.x;
    const int r0  = blockIdx.x * NROW;

    // Stage 16 rows of V and vagg (4096 floats, 16 per thread, coalesced).
    for (int x = tid; x < NROW * F; x += 256) {
        int r = x >> 7, k = x & 127;
        A[0][r][k] = v   [(long)(r0 + r) * F + k];
        A[1][r][k] = vagg[(long)(r0 + r) * F + k];
    }
    __syncthreads();

    const int c  = tid & 127;
    const int hs = tid >> 7;          // wave-uniform (waves 0-1 vs 2-3)
    const float* W = hs ? Wvn : Wvc;

    float acc[NROW];
    #pragma unroll
    for (int r = 0; r < NROW; ++r) acc[r] = 0.f;

    for (int k = 0; k < F; k += 4) {
        float w0 = W[(k + 0) * F + c];
        float w1 = W[(k + 1) * F + c];
        float w2 = W[(k + 2) * F + c];
        float w3 = W[(k + 3) * F + c];
        #pragma unroll
        for (int r = 0; r < NROW; ++r) {
            const float4 a = *(const float4*)&A[hs][r][k];  // LDS broadcast
            acc[r] = fmaf(a.x, w0, acc[r]);
            acc[r] = fmaf(a.y, w1, acc[r]);
            acc[r] = fmaf(a.z, w2, acc[r]);
            acc[r] = fmaf(a.w, w3, acc[r]);
        }
    }

    if (hs == 1) {
        #pragma unroll
        for (int r = 0; r < NROW; ++r) P[r][c] = acc[r];
    }
    __syncthreads();
    if (hs == 0) {
        float b = bv[c];
        #pragma unroll
        for (int r = 0; r < NROW; ++r) {
            float z = acc[r] + P[r][c] + b;
            out[(long)(r0 + r) * F + c] = fmaxf(z, 0.f);
        }
    }
}

// ---------------------------------------------------------------------------
extern "C" void kernel_launch(void* const* d_in, const int* in_sizes, int n_in,
                              void* d_out, int out_size, void* d_ws, size_t ws_size,
                              hipStream_t stream)
{
    const float* v       = (const float*)d_in[0];
    const int*   nh_idx  = (const int*)  d_in[1];
    const int*   int_idx = (const int*)  d_in[2];
    const float* nh_e    = (const float*)d_in[3];
    const float* int_e   = (const float*)d_in[4];
    const float* Wvc     = (const float*)d_in[5];
    const float* Wvn     = (const float*)d_in[6];
    const float* bv      = (const float*)d_in[7];
    float* out = (float*)d_out;

    // Kernel A writes vagg into d_out; kernel B reads it (own rows only) and
    // overwrites with the final result.
    agg_kernel<<<(N_VERT + 3) / 4, 256, 0, stream>>>(v, nh_idx, int_idx, nh_e, int_e, out);
    gemm_kernel<<<N_VERT / NROW, 256, 0, stream>>>(v, out, Wvc, Wvn, bv, out);
}

// Round 2
// 222.089 us; speedup vs baseline: 1.3337x; 1.3337x over previous
//
#include <hip/hip_runtime.h>

#define NV 50000
#define F 128
#define K 20
#define KCAT 256   // concatenated inner dim: [V | vagg]

typedef __attribute__((ext_vector_type(8))) __bf16 bf16x8;
typedef __attribute__((ext_vector_type(4))) float f32x4;

__device__ inline ushort f2bf(float x) {     // RNE f32 -> bf16
    uint u = __float_as_uint(x);
    return (ushort)((u + 0x7fffu + ((u >> 16) & 1u)) >> 16);
}

// ---------------------------------------------------------------------------
// ws layout (bf16 elements):
//   vb  = [NV][256]: cols 0..127 = bf16(V), cols 128..255 = bf16(vagg)
//   wt  = [128][256]: wt[c][k] = bf16(Wcat[k][c]), Wcat = [Wvc; Wvn]
// ---------------------------------------------------------------------------

// V fp32 -> bf16 into vb rows (cols 0..127). One float4 per thread.
__global__ __launch_bounds__(256) void conv_v(const float4* __restrict__ v4,
                                              ushort* __restrict__ vb) {
    int t = blockIdx.x * 256 + threadIdx.x;
    if (t >= NV * F / 4) return;
    int e = t * 4;
    int row = e >> 7, f = e & 127;
    float4 x = v4[t];
    uint2 o;
    o.x = (uint)f2bf(x.x) | ((uint)f2bf(x.y) << 16);
    o.y = (uint)f2bf(x.z) | ((uint)f2bf(x.w) << 16);
    *reinterpret_cast<uint2*>(vb + (size_t)row * KCAT + f) = o;
}

// Wt[c][k] = bf16(Wcat[k][c])  (tiny: 32768 elems)
__global__ __launch_bounds__(256) void conv_w(const float* __restrict__ Wvc,
                                              const float* __restrict__ Wvn,
                                              ushort* __restrict__ wt) {
    int t = blockIdx.x * 256 + threadIdx.x;
    if (t >= F * KCAT) return;
    int c = t >> 8, k = t & 255;
    float w = (k < F) ? Wvc[k * F + c] : Wvn[(k - F) * F + c];
    wt[t] = f2bf(w);
}

// ---------------------------------------------------------------------------
// agg: vagg[i,:] = (sum_k w_k * Vbf16[idx_k,:]) / denom_i, written as bf16
// into vb[i][128..255]. One wave per row; lane holds 2 features (uint = 2 bf16,
// 4 B/lane -> 256 B coalesced gather per row).
// Reads only cols 0..127 (uints 0..63), writes only uints 64..127 -> no race.
// ---------------------------------------------------------------------------
__global__ __launch_bounds__(256) void agg_kernel(
    const uint* __restrict__ vb_u,   // [NV][128] uint
    const int* __restrict__ nh_idx, const int* __restrict__ int_idx,
    const float* __restrict__ nh_e, const float* __restrict__ int_e,
    uint* __restrict__ vagg_u)       // same buffer as vb_u
{
    int row  = blockIdx.x * 4 + (threadIdx.x >> 6);
    int lane = threadIdx.x & 63;
    if (row >= NV) return;

    float ax = 0.f, ay = 0.f, cnt = (float)K;
    const long base = (long)row * K;

    #pragma unroll
    for (int k = 0; k < K; ++k) {
        int   j = nh_idx[base + k];
        float w = nh_e [base + k];
        uint  p = vb_u[(size_t)j * 128 + lane];
        ax = fmaf(w, __uint_as_float(p << 16), ax);
        ay = fmaf(w, __uint_as_float(p & 0xffff0000u), ay);
    }
    #pragma unroll
    for (int k = 0; k < K; ++k) {
        int j = int_idx[base + k];
        if (j != -1) {               // wave-uniform branch
            float w = int_e[base + k];
            uint  p = vb_u[(size_t)j * 128 + lane];
            ax = fmaf(w, __uint_as_float(p << 16), ax);
            ay = fmaf(w, __uint_as_float(p & 0xffff0000u), ay);
            cnt += 1.f;
        }
    }
    float inv = 1.f / cnt;
    vagg_u[(size_t)row * 128 + 64 + lane] =
        (uint)f2bf(ax * inv) | ((uint)f2bf(ay * inv) << 16);
}

// ---------------------------------------------------------------------------
// Fused MFMA GEMM: out = relu(vb[N,256] @ Wcat[256,128] + bv)
// Block = 4 waves, 64 rows; each wave 16 rows x 128 cols (8 col-tiles of
// 16x16x32 bf16, K=256 = 8 k-steps). A-frags from global (bf16 rows), B-frags
// from pre-transposed Wt (contiguous 16 B per lane, L2-resident 64 KB).
// Layouts: A row=lane&15, k=(lane>>4)*8+j ; D col=lane&15, row=(lane>>4)*4+reg.
// ---------------------------------------------------------------------------
__global__ __launch_bounds__(256) void gemm_kernel(
    const ushort* __restrict__ vb,   // [NV][256] bf16
    const ushort* __restrict__ wt,   // [128][256] bf16
    const float* __restrict__ bv,
    float* __restrict__ out)
{
    const int lane = threadIdx.x & 63;
    const int wave = threadIdx.x >> 6;
    const int r0   = blockIdx.x * 64 + wave * 16;

    int arow = r0 + (lane & 15);
    if (arow >= NV) arow = NV - 1;           // clamp loads; stores guarded

    const bf16x8* abase = reinterpret_cast<const bf16x8*>(
        vb + (size_t)arow * KCAT + (lane >> 4) * 8);
    bf16x8 a[8];
    #pragma unroll
    for (int ks = 0; ks < 8; ++ks) a[ks] = abase[ks * 4];   // stride 32 bf16

    f32x4 acc[8];
    #pragma unroll
    for (int ct = 0; ct < 8; ++ct) acc[ct] = (f32x4){0.f, 0.f, 0.f, 0.f};

    const ushort* wbase = wt + (size_t)(lane & 15) * KCAT + (lane >> 4) * 8;
    #pragma unroll
    for (int ct = 0; ct < 8; ++ct) {
        const bf16x8* wb = reinterpret_cast<const bf16x8*>(
            wbase + (size_t)ct * 16 * KCAT);
        #pragma unroll
        for (int ks = 0; ks < 8; ++ks) {
            bf16x8 b = wb[ks * 4];
            acc[ct] = __builtin_amdgcn_mfma_f32_16x16x32_bf16(a[ks], b, acc[ct], 0, 0, 0);
        }
    }

    const int col0  = lane & 15;
    const int rbase = r0 + (lane >> 4) * 4;
    #pragma unroll
    for (int ct = 0; ct < 8; ++ct) {
        int c = ct * 16 + col0;
        float bb = bv[c];
        #pragma unroll
        for (int reg = 0; reg < 4; ++reg) {
            int r = rbase + reg;
            if (r < NV) {
                float z = acc[ct][reg] + bb;
                out[(size_t)r * F + c] = fmaxf(z, 0.f);
            }
        }
    }
}

// ---------------------------------------------------------------------------
extern "C" void kernel_launch(void* const* d_in, const int* in_sizes, int n_in,
                              void* d_out, int out_size, void* d_ws, size_t ws_size,
                              hipStream_t stream)
{
    const float* v       = (const float*)d_in[0];
    const int*   nh_idx  = (const int*)  d_in[1];
    const int*   int_idx = (const int*)  d_in[2];
    const float* nh_e    = (const float*)d_in[3];
    const float* int_e   = (const float*)d_in[4];
    const float* Wvc     = (const float*)d_in[5];
    const float* Wvn     = (const float*)d_in[6];
    const float* bv      = (const float*)d_in[7];
    float* out = (float*)d_out;

    ushort* vb = (ushort*)d_ws;                       // NV*256 bf16 = 25.6 MB
    ushort* wt = vb + (size_t)NV * KCAT;              // 128*256 bf16 = 64 KB

    conv_v<<<(NV * F / 4) / 256, 256, 0, stream>>>((const float4*)v, vb);
    conv_w<<<(F * KCAT + 255) / 256, 256, 0, stream>>>(Wvc, Wvn, wt);
    agg_kernel<<<(NV + 3) / 4, 256, 0, stream>>>((const uint*)vb, nh_idx, int_idx,
                                                 nh_e, int_e, (uint*)vb);
    gemm_kernel<<<(NV + 63) / 64, 256, 0, stream>>>(vb, wt, bv, out);
}

// Round 3
// 204.148 us; speedup vs baseline: 1.4509x; 1.0879x over previous
//
#include <hip/hip_runtime.h>

#define NV 50000
#define F 128
#define K 20
#define KCAT 256   // concatenated inner dim: [V | vagg]

typedef __attribute__((ext_vector_type(8))) __bf16 bf16x8;
typedef __attribute__((ext_vector_type(4))) float f32x4;

__device__ inline ushort f2bf(float x) {     // RNE f32 -> bf16
    uint u = __float_as_uint(x);
    return (ushort)((u + 0x7fffu + ((u >> 16) & 1u)) >> 16);
}

// ws layout (bf16): vb=[NV][256] (cols 0..127 = bf16(V), 128..255 = bf16(vagg))
//                   wt=[128][256] wt[c][k] = bf16(Wcat[k][c])

// ---------------------------------------------------------------------------
// prep: blocks 0..6249 convert V fp32->bf16 (float4/thread); remaining 128
// blocks build the transposed bf16 weight matrix.
// ---------------------------------------------------------------------------
__global__ __launch_bounds__(256) void prep_kernel(
    const float4* __restrict__ v4, ushort* __restrict__ vb,
    const float* __restrict__ Wvc, const float* __restrict__ Wvn,
    ushort* __restrict__ wt)
{
    int bid = blockIdx.x;
    if (bid < NV * F / 4 / 256) {          // 6250 blocks
        int t = bid * 256 + threadIdx.x;
        int e = t * 4;
        int row = e >> 7, f = e & 127;
        float4 x = v4[t];
        uint2 o;
        o.x = (uint)f2bf(x.x) | ((uint)f2bf(x.y) << 16);
        o.y = (uint)f2bf(x.z) | ((uint)f2bf(x.w) << 16);
        *reinterpret_cast<uint2*>(vb + (size_t)row * KCAT + f) = o;
    } else {
        int t = (bid - NV * F / 4 / 256) * 256 + threadIdx.x;  // < 32768
        int c = t >> 8, k = t & 255;
        float w = (k < F) ? Wvc[k * F + c] : Wvn[(k - F) * F + c];
        wt[t] = f2bf(w);
    }
}

// ---------------------------------------------------------------------------
// agg (feature-sliced): slice = bid & 3 -> 32 features = 16 uints = 64B/row.
// With bid%8 -> XCD round-robin, each XCD gathers only from a 3.2 MB slice
// that fits its private 4 MB L2. 16 rows/block (4/wave, 16 lanes/row).
// Reads vb uints [16s,16s+16); writes uints [64+16s, 64+16s+16) -> no race.
// ---------------------------------------------------------------------------
__global__ __launch_bounds__(256) void agg_sliced(
    const uint* __restrict__ vb_u,   // [NV][128] uint view
    const int* __restrict__ nh_idx, const int* __restrict__ int_idx,
    const float* __restrict__ nh_e, const float* __restrict__ int_e,
    uint* __restrict__ vagg_u)       // same buffer
{
    const int bid   = blockIdx.x;
    const int slice = bid & 3;
    const int rb    = bid >> 2;
    const int lane  = threadIdx.x & 63;
    const int wave  = threadIdx.x >> 6;
    const int row   = rb * 16 + wave * 4 + (lane >> 4);
    const int q     = lane & 15;
    const uint* __restrict__ src = vb_u + slice * 16 + q;

    float ax = 0.f, ay = 0.f, cnt = (float)K;
    const long base = (long)row * K;

    #pragma unroll
    for (int k = 0; k < K; ++k) {
        int   j = nh_idx[base + k];
        float w = nh_e [base + k];
        uint  p = src[(size_t)j * 128];
        ax = fmaf(w, __uint_as_float(p << 16), ax);
        ay = fmaf(w, __uint_as_float(p & 0xffff0000u), ay);
    }
    #pragma unroll
    for (int k = 0; k < K; ++k) {
        int   j = int_idx[base + k];
        float w = int_e [base + k];
        bool  valid = (j >= 0);
        if (!valid) { j = 0; w = 0.f; }   // predicated; row 0 stays hot
        uint  p = src[(size_t)j * 128];
        ax = fmaf(w, __uint_as_float(p << 16), ax);
        ay = fmaf(w, __uint_as_float(p & 0xffff0000u), ay);
        cnt += valid ? 1.f : 0.f;
    }
    float inv = 1.f / cnt;
    vagg_u[(size_t)row * 128 + 64 + slice * 16 + q] =
        (uint)f2bf(ax * inv) | ((uint)f2bf(ay * inv) << 16);
}

// ---------------------------------------------------------------------------
// Fused MFMA GEMM: out = relu(vb[N,256] @ Wcat[256,128] + bv)
// (unchanged from round 2 — verified correct; renamed for profiling clarity)
// ---------------------------------------------------------------------------
__global__ __launch_bounds__(256) void gemm_fused(
    const ushort* __restrict__ vb,   // [NV][256] bf16
    const ushort* __restrict__ wt,   // [128][256] bf16
    const float* __restrict__ bv,
    float* __restrict__ out)
{
    const int lane = threadIdx.x & 63;
    const int wave = threadIdx.x >> 6;
    const int r0   = blockIdx.x * 64 + wave * 16;

    int arow = r0 + (lane & 15);
    if (arow >= NV) arow = NV - 1;           // clamp loads; stores guarded

    const bf16x8* abase = reinterpret_cast<const bf16x8*>(
        vb + (size_t)arow * KCAT + (lane >> 4) * 8);
    bf16x8 a[8];
    #pragma unroll
    for (int ks = 0; ks < 8; ++ks) a[ks] = abase[ks * 4];   // stride 32 bf16

    f32x4 acc[8];
    #pragma unroll
    for (int ct = 0; ct < 8; ++ct) acc[ct] = (f32x4){0.f, 0.f, 0.f, 0.f};

    const ushort* wbase = wt + (size_t)(lane & 15) * KCAT + (lane >> 4) * 8;
    #pragma unroll
    for (int ct = 0; ct < 8; ++ct) {
        const bf16x8* wb = reinterpret_cast<const bf16x8*>(
            wbase + (size_t)ct * 16 * KCAT);
        #pragma unroll
        for (int ks = 0; ks < 8; ++ks) {
            bf16x8 b = wb[ks * 4];
            acc[ct] = __builtin_amdgcn_mfma_f32_16x16x32_bf16(a[ks], b, acc[ct], 0, 0, 0);
        }
    }

    const int col0  = lane & 15;
    const int rbase = r0 + (lane >> 4) * 4;
    #pragma unroll
    for (int ct = 0; ct < 8; ++ct) {
        int c = ct * 16 + col0;
        float bb = bv[c];
        #pragma unroll
        for (int reg = 0; reg < 4; ++reg) {
            int r = rbase + reg;
            if (r < NV) {
                float z = acc[ct][reg] + bb;
                out[(size_t)r * F + c] = fmaxf(z, 0.f);
            }
        }
    }
}

// ---------------------------------------------------------------------------
extern "C" void kernel_launch(void* const* d_in, const int* in_sizes, int n_in,
                              void* d_out, int out_size, void* d_ws, size_t ws_size,
                              hipStream_t stream)
{
    const float* v       = (const float*)d_in[0];
    const int*   nh_idx  = (const int*)  d_in[1];
    const int*   int_idx = (const int*)  d_in[2];
    const float* nh_e    = (const float*)d_in[3];
    const float* int_e   = (const float*)d_in[4];
    const float* Wvc     = (const float*)d_in[5];
    const float* Wvn     = (const float*)d_in[6];
    const float* bv      = (const float*)d_in[7];
    float* out = (float*)d_out;

    ushort* vb = (ushort*)d_ws;                       // NV*256 bf16 = 25.6 MB
    ushort* wt = vb + (size_t)NV * KCAT;              // 128*256 bf16 = 64 KB

    prep_kernel<<<NV * F / 4 / 256 + F * KCAT / 256, 256, 0, stream>>>(
        (const float4*)v, vb, Wvc, Wvn, wt);
    agg_sliced<<<(NV / 16) * 4, 256, 0, stream>>>((const uint*)vb, nh_idx, int_idx,
                                                  nh_e, int_e, (uint*)vb);
    gemm_fused<<<(NV + 63) / 64, 256, 0, stream>>>(vb, wt, bv, out);
}